// Round 1
// baseline (1168.878 us; speedup 1.0000x reference)
//
#include <hip/hip_runtime.h>

#define DD 128
#define LN_EPS 1e-5f

__device__ __forceinline__ float sigmoidf(float x) {
  return 1.0f / (1.0f + __expf(-x));
}

// ---------------------------------------------------------------------------
// Kernel 1: node-level dual GEMM.
// P[r, d] = (h[r] @ msg_W)[d] * sigmoid((h[r] @ gate_W)[d]),  r in [0, BN)
// Tile: 32 rows x 128 cols per block, 256 threads.
// tx = t&31 -> 4 cols each (float4), ty = t>>5 -> 4 rows each.
// ---------------------------------------------------------------------------
__global__ __launch_bounds__(256) void k_node(
    const float* __restrict__ h, const float* __restrict__ gate_W,
    const float* __restrict__ msg_W, float* __restrict__ P, int BN)
{
  __shared__ float As[32][33];  // +1 pad breaks bank conflicts on As[r][kk]
  const int t  = threadIdx.x;
  const int tx = t & 31;
  const int ty = t >> 5;
  const int row0 = blockIdx.x * 32;

  float accg[4][4];
  float accm[4][4];
#pragma unroll
  for (int i = 0; i < 4; i++)
#pragma unroll
    for (int j = 0; j < 4; j++) { accg[i][j] = 0.f; accm[i][j] = 0.f; }

  const int lrow = t >> 3;        // 0..31
  const int lk4  = (t & 7) << 2;  // 0..28 step 4
  int grow = row0 + lrow; if (grow >= BN) grow = BN - 1;

  for (int k0 = 0; k0 < DD; k0 += 32) {
    const float4 av = *(const float4*)(h + (size_t)grow * DD + k0 + lk4);
    As[lrow][lk4 + 0] = av.x; As[lrow][lk4 + 1] = av.y;
    As[lrow][lk4 + 2] = av.z; As[lrow][lk4 + 3] = av.w;
    __syncthreads();
#pragma unroll 4
    for (int kk = 0; kk < 32; kk++) {
      const float4 gw = *(const float4*)(gate_W + (size_t)(k0 + kk) * DD + (tx << 2));
      const float4 mw = *(const float4*)(msg_W  + (size_t)(k0 + kk) * DD + (tx << 2));
      float a[4];
#pragma unroll
      for (int rr = 0; rr < 4; rr++) a[rr] = As[ty * 4 + rr][kk];
#pragma unroll
      for (int rr = 0; rr < 4; rr++) {
        accg[rr][0] += a[rr] * gw.x; accg[rr][1] += a[rr] * gw.y;
        accg[rr][2] += a[rr] * gw.z; accg[rr][3] += a[rr] * gw.w;
        accm[rr][0] += a[rr] * mw.x; accm[rr][1] += a[rr] * mw.y;
        accm[rr][2] += a[rr] * mw.z; accm[rr][3] += a[rr] * mw.w;
      }
    }
    __syncthreads();
  }

#pragma unroll
  for (int rr = 0; rr < 4; rr++) {
    const int row = row0 + ty * 4 + rr;
    if (row < BN) {
      float4 o;
      o.x = accm[rr][0] * sigmoidf(accg[rr][0]);
      o.y = accm[rr][1] * sigmoidf(accg[rr][1]);
      o.z = accm[rr][2] * sigmoidf(accg[rr][2]);
      o.w = accm[rr][3] * sigmoidf(accg[rr][3]);
      *(float4*)(P + (size_t)row * DD + (tx << 2)) = o;
    }
  }
}

// ---------------------------------------------------------------------------
// Kernel 2: edge scatter. One 64-lane wave per edge; lane covers 2 cols.
// msg[b,e,d] = P[b, src[e], d] * rel_emb[rel[e], d]; h_agg[b, tgt[e], d] += msg
// ---------------------------------------------------------------------------
__global__ __launch_bounds__(256) void k_edge(
    const float* __restrict__ P, const float* __restrict__ rel_emb,
    const int* __restrict__ esrc, const int* __restrict__ etgt,
    const int* __restrict__ erel, const int* __restrict__ nE_ptr,
    float* __restrict__ h_agg, int E, int BN)
{
  const int gw = (int)((blockIdx.x * blockDim.x + threadIdx.x) >> 6);
  if (gw >= E) return;
  const int lane = threadIdx.x & 63;
  const int N = *nE_ptr;
  const int B = BN / N;

  const int s  = esrc[gw];
  const int tg = etgt[gw];
  const int r  = erel[gw];

  const float2 rv = *(const float2*)(rel_emb + (size_t)r * DD + lane * 2);
  for (int b = 0; b < B; b++) {
    const float2 p = *(const float2*)(P + ((size_t)b * N + s) * DD + lane * 2);
    float* dst = h_agg + ((size_t)b * N + tg) * DD + lane * 2;
    unsafeAtomicAdd(dst + 0, p.x * rv.x);
    unsafeAtomicAdd(dst + 1, p.y * rv.y);
  }
}

// ---------------------------------------------------------------------------
// Kernel 3: upd = [h, h_agg] @ update_W + b; x = h + relu(upd); LayerNorm(x).
// Same tiling as k_node; block owns full 128-col rows so LN fuses in-epilogue
// via half-wave shuffle butterfly (tx spans lanes 0..31 of each half-wave).
// ---------------------------------------------------------------------------
__global__ __launch_bounds__(256) void k_update_ln(
    const float* __restrict__ h, const float* __restrict__ h_agg,
    const float* __restrict__ upd_W, const float* __restrict__ upd_b,
    const float* __restrict__ gamma, const float* __restrict__ beta,
    float* __restrict__ out, int BN)
{
  __shared__ float As[32][33];
  const int t  = threadIdx.x;
  const int tx = t & 31;
  const int ty = t >> 5;
  const int row0 = blockIdx.x * 32;

  float acc[4][4];
#pragma unroll
  for (int i = 0; i < 4; i++)
#pragma unroll
    for (int j = 0; j < 4; j++) acc[i][j] = 0.f;

  const int lrow = t >> 3;
  const int lk4  = (t & 7) << 2;
  int grow = row0 + lrow; if (grow >= BN) grow = BN - 1;

  for (int ph = 0; ph < 2; ph++) {
    const float* A = ph ? h_agg : h;
    const float* W = upd_W + (size_t)ph * DD * DD;
    for (int k0 = 0; k0 < DD; k0 += 32) {
      const float4 av = *(const float4*)(A + (size_t)grow * DD + k0 + lk4);
      As[lrow][lk4 + 0] = av.x; As[lrow][lk4 + 1] = av.y;
      As[lrow][lk4 + 2] = av.z; As[lrow][lk4 + 3] = av.w;
      __syncthreads();
#pragma unroll 4
      for (int kk = 0; kk < 32; kk++) {
        const float4 w = *(const float4*)(W + (size_t)(k0 + kk) * DD + (tx << 2));
        float a[4];
#pragma unroll
        for (int rr = 0; rr < 4; rr++) a[rr] = As[ty * 4 + rr][kk];
#pragma unroll
        for (int rr = 0; rr < 4; rr++) {
          acc[rr][0] += a[rr] * w.x; acc[rr][1] += a[rr] * w.y;
          acc[rr][2] += a[rr] * w.z; acc[rr][3] += a[rr] * w.w;
        }
      }
      __syncthreads();
    }
  }

  const float4 bv  = *(const float4*)(upd_b + (tx << 2));
  const float4 gv  = *(const float4*)(gamma + (tx << 2));
  const float4 btv = *(const float4*)(beta  + (tx << 2));

  float xv[4][4];
  float s1[4], s2[4];
#pragma unroll
  for (int rr = 0; rr < 4; rr++) {
    int row = row0 + ty * 4 + rr; if (row >= BN) row = BN - 1;
    const float4 hv = *(const float4*)(h + (size_t)row * DD + (tx << 2));
    xv[rr][0] = hv.x + fmaxf(acc[rr][0] + bv.x, 0.f);
    xv[rr][1] = hv.y + fmaxf(acc[rr][1] + bv.y, 0.f);
    xv[rr][2] = hv.z + fmaxf(acc[rr][2] + bv.z, 0.f);
    xv[rr][3] = hv.w + fmaxf(acc[rr][3] + bv.w, 0.f);
    s1[rr] = xv[rr][0] + xv[rr][1] + xv[rr][2] + xv[rr][3];
    s2[rr] = xv[rr][0] * xv[rr][0] + xv[rr][1] * xv[rr][1] +
             xv[rr][2] * xv[rr][2] + xv[rr][3] * xv[rr][3];
  }

  // butterfly over the 32 tx lanes (stays within each half-wave: masks < 32)
#pragma unroll
  for (int m = 1; m <= 16; m <<= 1) {
#pragma unroll
    for (int rr = 0; rr < 4; rr++) {
      s1[rr] += __shfl_xor(s1[rr], m, 64);
      s2[rr] += __shfl_xor(s2[rr], m, 64);
    }
  }

#pragma unroll
  for (int rr = 0; rr < 4; rr++) {
    const int row = row0 + ty * 4 + rr;
    if (row < BN) {
      const float mu   = s1[rr] * (1.0f / DD);
      const float var  = s2[rr] * (1.0f / DD) - mu * mu;
      const float rstd = rsqrtf(var + LN_EPS);
      float4 o;
      o.x = (xv[rr][0] - mu) * rstd * gv.x + btv.x;
      o.y = (xv[rr][1] - mu) * rstd * gv.y + btv.y;
      o.z = (xv[rr][2] - mu) * rstd * gv.z + btv.z;
      o.w = (xv[rr][3] - mu) * rstd * gv.w + btv.w;
      *(float4*)(out + (size_t)row * DD + (tx << 2)) = o;
    }
  }
}

// ---------------------------------------------------------------------------
extern "C" void kernel_launch(void* const* d_in, const int* in_sizes, int n_in,
                              void* d_out, int out_size, void* d_ws, size_t ws_size,
                              hipStream_t stream) {
  const float* h       = (const float*)d_in[0];
  const int*   esrc    = (const int*)d_in[1];
  const int*   etgt    = (const int*)d_in[2];
  const int*   erel    = (const int*)d_in[3];
  const int*   nE_ptr  = (const int*)d_in[4];
  const float* msg_W   = (const float*)d_in[5];
  const float* rel_emb = (const float*)d_in[6];
  const float* gate_W  = (const float*)d_in[7];
  const float* upd_W   = (const float*)d_in[8];
  const float* upd_b   = (const float*)d_in[9];
  const float* gamma   = (const float*)d_in[10];
  const float* beta    = (const float*)d_in[11];
  float*       out     = (float*)d_out;

  const int E  = in_sizes[1];
  const int BN = in_sizes[0] / DD;   // B*N rows

  float* P     = (float*)d_ws;                  // BN*DD floats
  float* h_agg = P + (size_t)BN * DD;           // BN*DD floats

  hipMemsetAsync(h_agg, 0, (size_t)BN * DD * sizeof(float), stream);

  k_node<<<(BN + 31) / 32, 256, 0, stream>>>(h, gate_W, msg_W, P, BN);
  k_edge<<<(E + 3) / 4, 256, 0, stream>>>(P, rel_emb, esrc, etgt, erel,
                                          nE_ptr, h_agg, E, BN);
  k_update_ln<<<(BN + 31) / 32, 256, 0, stream>>>(h, h_agg, upd_W, upd_b,
                                                  gamma, beta, out, BN);
}

// Round 2
// 504.777 us; speedup vs baseline: 2.3156x; 2.3156x over previous
//
#include <hip/hip_runtime.h>

#define DD 128
#define NN 50000      // nodes (N)
#define BB 2          // batch
#define EE 500000     // edges
#define LN_EPS 1e-5f

__device__ __forceinline__ float sigmoidf(float x) {
  return 1.0f / (1.0f + __expf(-x));
}

// ---------------------------------------------------------------------------
// Kernel 1: node-level dual GEMM.
// P[r, d] = (h[r] @ msg_W)[d] * sigmoid((h[r] @ gate_W)[d]),  r in [0, BN)
// ---------------------------------------------------------------------------
__global__ __launch_bounds__(256) void k_node(
    const float* __restrict__ h, const float* __restrict__ gate_W,
    const float* __restrict__ msg_W, float* __restrict__ P, int BN)
{
  __shared__ float As[32][33];
  const int t  = threadIdx.x;
  const int tx = t & 31;
  const int ty = t >> 5;
  const int row0 = blockIdx.x * 32;

  float accg[4][4];
  float accm[4][4];
#pragma unroll
  for (int i = 0; i < 4; i++)
#pragma unroll
    for (int j = 0; j < 4; j++) { accg[i][j] = 0.f; accm[i][j] = 0.f; }

  const int lrow = t >> 3;
  const int lk4  = (t & 7) << 2;
  int grow = row0 + lrow; if (grow >= BN) grow = BN - 1;

  for (int k0 = 0; k0 < DD; k0 += 32) {
    const float4 av = *(const float4*)(h + (size_t)grow * DD + k0 + lk4);
    As[lrow][lk4 + 0] = av.x; As[lrow][lk4 + 1] = av.y;
    As[lrow][lk4 + 2] = av.z; As[lrow][lk4 + 3] = av.w;
    __syncthreads();
#pragma unroll 4
    for (int kk = 0; kk < 32; kk++) {
      const float4 gw = *(const float4*)(gate_W + (size_t)(k0 + kk) * DD + (tx << 2));
      const float4 mw = *(const float4*)(msg_W  + (size_t)(k0 + kk) * DD + (tx << 2));
      float a[4];
#pragma unroll
      for (int rr = 0; rr < 4; rr++) a[rr] = As[ty * 4 + rr][kk];
#pragma unroll
      for (int rr = 0; rr < 4; rr++) {
        accg[rr][0] += a[rr] * gw.x; accg[rr][1] += a[rr] * gw.y;
        accg[rr][2] += a[rr] * gw.z; accg[rr][3] += a[rr] * gw.w;
        accm[rr][0] += a[rr] * mw.x; accm[rr][1] += a[rr] * mw.y;
        accm[rr][2] += a[rr] * mw.z; accm[rr][3] += a[rr] * mw.w;
      }
    }
    __syncthreads();
  }

#pragma unroll
  for (int rr = 0; rr < 4; rr++) {
    const int row = row0 + ty * 4 + rr;
    if (row < BN) {
      float4 o;
      o.x = accm[rr][0] * sigmoidf(accg[rr][0]);
      o.y = accm[rr][1] * sigmoidf(accg[rr][1]);
      o.z = accm[rr][2] * sigmoidf(accg[rr][2]);
      o.w = accm[rr][3] * sigmoidf(accg[rr][3]);
      *(float4*)(P + (size_t)row * DD + (tx << 2)) = o;
    }
  }
}

// ---------------------------------------------------------------------------
// CSR build: histogram -> block scans -> fill (counting sort by target).
// ---------------------------------------------------------------------------
__global__ __launch_bounds__(256) void k_hist(
    const int* __restrict__ etgt, int* __restrict__ deg)
{
  const int e = blockIdx.x * 256 + threadIdx.x;
  if (e < EE) atomicAdd(&deg[etgt[e]], 1);
}

__global__ __launch_bounds__(256) void k_scan_block(
    const int* __restrict__ deg, int* __restrict__ rstart,
    int* __restrict__ bsum, int N)
{
  __shared__ int s[256];
  const int i = blockIdx.x * 256 + threadIdx.x;
  const int v = (i < N) ? deg[i] : 0;
  s[threadIdx.x] = v;
  __syncthreads();
#pragma unroll
  for (int off = 1; off < 256; off <<= 1) {
    const int t = (threadIdx.x >= off) ? s[threadIdx.x - off] : 0;
    __syncthreads();
    s[threadIdx.x] += t;
    __syncthreads();
  }
  if (i < N) rstart[i] = s[threadIdx.x] - v;      // exclusive, block-local
  if (threadIdx.x == 255) bsum[blockIdx.x] = s[255];
}

__global__ __launch_bounds__(256) void k_scan_small(
    int* __restrict__ bsum, int* __restrict__ boff, int nb)
{
  __shared__ int s[256];
  const int v = (threadIdx.x < nb) ? bsum[threadIdx.x] : 0;
  s[threadIdx.x] = v;
  __syncthreads();
#pragma unroll
  for (int off = 1; off < 256; off <<= 1) {
    const int t = (threadIdx.x >= off) ? s[threadIdx.x - off] : 0;
    __syncthreads();
    s[threadIdx.x] += t;
    __syncthreads();
  }
  if (threadIdx.x < nb) boff[threadIdx.x] = s[threadIdx.x] - v;  // exclusive
}

__global__ __launch_bounds__(256) void k_add_off(
    int* __restrict__ rstart, const int* __restrict__ boff,
    int* __restrict__ cur, int N)
{
  const int i = blockIdx.x * 256 + threadIdx.x;
  if (i < N) {
    const int v = rstart[i] + boff[blockIdx.x];
    rstart[i] = v;
    cur[i] = v;
  }
}

__global__ __launch_bounds__(256) void k_fill(
    const int* __restrict__ esrc, const int* __restrict__ etgt,
    const int* __restrict__ erel, int* __restrict__ cur,
    int* __restrict__ packed)
{
  const int e = blockIdx.x * 256 + threadIdx.x;
  if (e < EE) {
    const int pos = atomicAdd(&cur[etgt[e]], 1);
    packed[pos] = esrc[e] | (erel[e] << 16);   // src < 2^16, rel < 2^9
  }
}

// ---------------------------------------------------------------------------
// Kernel 2': gather-side aggregation. One wave per target node, no atomics.
// h_agg[b, n, :] = sum over incoming edges of P[b, src] * rel_emb[rel]
// ---------------------------------------------------------------------------
__global__ __launch_bounds__(256) void k_agg(
    const float* __restrict__ P, const float* __restrict__ rel_emb,
    const int* __restrict__ rstart, const int* __restrict__ packed,
    float* __restrict__ h_agg)
{
  const int node = blockIdx.x * 4 + (threadIdx.x >> 6);
  if (node >= NN) return;
  const int lane = threadIdx.x & 63;

  const int beg = rstart[node];
  const int end = (node == NN - 1) ? EE : rstart[node + 1];

  float2 a0 = {0.f, 0.f}, a1 = {0.f, 0.f};
  for (int j = beg; j < end; j++) {
    const int p   = packed[j];          // wave-uniform -> scalar load
    const int src = p & 0xFFFF;
    const int rel = p >> 16;
    const float2 rv = *(const float2*)(rel_emb + (size_t)rel * DD + lane * 2);
    const float2 p0 = *(const float2*)(P + (size_t)src * DD + lane * 2);
    const float2 p1 = *(const float2*)(P + ((size_t)NN + src) * DD + lane * 2);
    a0.x += p0.x * rv.x; a0.y += p0.y * rv.y;
    a1.x += p1.x * rv.x; a1.y += p1.y * rv.y;
  }
  *(float2*)(h_agg + (size_t)node * DD + lane * 2) = a0;
  *(float2*)(h_agg + ((size_t)NN + node) * DD + lane * 2) = a1;
}

// ---------------------------------------------------------------------------
// Kernel 3: upd = [h, h_agg] @ update_W + b; x = h + relu(upd); LayerNorm(x).
// ---------------------------------------------------------------------------
__global__ __launch_bounds__(256) void k_update_ln(
    const float* __restrict__ h, const float* __restrict__ h_agg,
    const float* __restrict__ upd_W, const float* __restrict__ upd_b,
    const float* __restrict__ gamma, const float* __restrict__ beta,
    float* __restrict__ out, int BN)
{
  __shared__ float As[32][33];
  const int t  = threadIdx.x;
  const int tx = t & 31;
  const int ty = t >> 5;
  const int row0 = blockIdx.x * 32;

  float acc[4][4];
#pragma unroll
  for (int i = 0; i < 4; i++)
#pragma unroll
    for (int j = 0; j < 4; j++) acc[i][j] = 0.f;

  const int lrow = t >> 3;
  const int lk4  = (t & 7) << 2;
  int grow = row0 + lrow; if (grow >= BN) grow = BN - 1;

  for (int ph = 0; ph < 2; ph++) {
    const float* A = ph ? h_agg : h;
    const float* W = upd_W + (size_t)ph * DD * DD;
    for (int k0 = 0; k0 < DD; k0 += 32) {
      const float4 av = *(const float4*)(A + (size_t)grow * DD + k0 + lk4);
      As[lrow][lk4 + 0] = av.x; As[lrow][lk4 + 1] = av.y;
      As[lrow][lk4 + 2] = av.z; As[lrow][lk4 + 3] = av.w;
      __syncthreads();
#pragma unroll 4
      for (int kk = 0; kk < 32; kk++) {
        const float4 w = *(const float4*)(W + (size_t)(k0 + kk) * DD + (tx << 2));
        float a[4];
#pragma unroll
        for (int rr = 0; rr < 4; rr++) a[rr] = As[ty * 4 + rr][kk];
#pragma unroll
        for (int rr = 0; rr < 4; rr++) {
          acc[rr][0] += a[rr] * w.x; acc[rr][1] += a[rr] * w.y;
          acc[rr][2] += a[rr] * w.z; acc[rr][3] += a[rr] * w.w;
        }
      }
      __syncthreads();
    }
  }

  const float4 bv  = *(const float4*)(upd_b + (tx << 2));
  const float4 gv  = *(const float4*)(gamma + (tx << 2));
  const float4 btv = *(const float4*)(beta  + (tx << 2));

  float xv[4][4];
  float s1[4], s2[4];
#pragma unroll
  for (int rr = 0; rr < 4; rr++) {
    int row = row0 + ty * 4 + rr; if (row >= BN) row = BN - 1;
    const float4 hv = *(const float4*)(h + (size_t)row * DD + (tx << 2));
    xv[rr][0] = hv.x + fmaxf(acc[rr][0] + bv.x, 0.f);
    xv[rr][1] = hv.y + fmaxf(acc[rr][1] + bv.y, 0.f);
    xv[rr][2] = hv.z + fmaxf(acc[rr][2] + bv.z, 0.f);
    xv[rr][3] = hv.w + fmaxf(acc[rr][3] + bv.w, 0.f);
    s1[rr] = xv[rr][0] + xv[rr][1] + xv[rr][2] + xv[rr][3];
    s2[rr] = xv[rr][0] * xv[rr][0] + xv[rr][1] * xv[rr][1] +
             xv[rr][2] * xv[rr][2] + xv[rr][3] * xv[rr][3];
  }

#pragma unroll
  for (int m = 1; m <= 16; m <<= 1) {
#pragma unroll
    for (int rr = 0; rr < 4; rr++) {
      s1[rr] += __shfl_xor(s1[rr], m, 64);
      s2[rr] += __shfl_xor(s2[rr], m, 64);
    }
  }

#pragma unroll
  for (int rr = 0; rr < 4; rr++) {
    const int row = row0 + ty * 4 + rr;
    if (row < BN) {
      const float mu   = s1[rr] * (1.0f / DD);
      const float var  = s2[rr] * (1.0f / DD) - mu * mu;
      const float rstd = rsqrtf(var + LN_EPS);
      float4 o;
      o.x = (xv[rr][0] - mu) * rstd * gv.x + btv.x;
      o.y = (xv[rr][1] - mu) * rstd * gv.y + btv.y;
      o.z = (xv[rr][2] - mu) * rstd * gv.z + btv.z;
      o.w = (xv[rr][3] - mu) * rstd * gv.w + btv.w;
      *(float4*)(out + (size_t)row * DD + (tx << 2)) = o;
    }
  }
}

// ---------------------------------------------------------------------------
extern "C" void kernel_launch(void* const* d_in, const int* in_sizes, int n_in,
                              void* d_out, int out_size, void* d_ws, size_t ws_size,
                              hipStream_t stream) {
  const float* h       = (const float*)d_in[0];
  const int*   esrc    = (const int*)d_in[1];
  const int*   etgt    = (const int*)d_in[2];
  const int*   erel    = (const int*)d_in[3];
  const float* msg_W   = (const float*)d_in[5];
  const float* rel_emb = (const float*)d_in[6];
  const float* gate_W  = (const float*)d_in[7];
  const float* upd_W   = (const float*)d_in[8];
  const float* upd_b   = (const float*)d_in[9];
  const float* gamma   = (const float*)d_in[10];
  const float* beta    = (const float*)d_in[11];
  float*       out     = (float*)d_out;

  const int BN = in_sizes[0] / DD;   // B*N rows = 100000

  float* P      = (float*)d_ws;                    // BN*DD floats (51.2 MB)
  float* h_agg  = P + (size_t)BN * DD;             // BN*DD floats (51.2 MB)
  int*   deg    = (int*)(h_agg + (size_t)BN * DD); // NN
  int*   rstart = deg + NN;                        // NN
  int*   cur    = rstart + NN;                     // NN
  int*   bsum   = cur + NN;                        // 256
  int*   boff   = bsum + 256;                      // 256
  int*   packed = boff + 256;                      // EE (2 MB)

  const int nbN = (NN + 255) / 256;   // 196 blocks over nodes
  const int nbE = (EE + 255) / 256;

  hipMemsetAsync(deg, 0, NN * sizeof(int), stream);

  k_node<<<(BN + 31) / 32, 256, 0, stream>>>(h, gate_W, msg_W, P, BN);

  k_hist<<<nbE, 256, 0, stream>>>(etgt, deg);
  k_scan_block<<<nbN, 256, 0, stream>>>(deg, rstart, bsum, NN);
  k_scan_small<<<1, 256, 0, stream>>>(bsum, boff, nbN);
  k_add_off<<<nbN, 256, 0, stream>>>(rstart, boff, cur, NN);
  k_fill<<<nbE, 256, 0, stream>>>(esrc, etgt, erel, cur, packed);

  k_agg<<<(NN + 3) / 4, 256, 0, stream>>>(P, rel_emb, rstart, packed, h_agg);

  k_update_ln<<<(BN + 31) / 32, 256, 0, stream>>>(h, h_agg, upd_W, upd_b,
                                                  gamma, beta, out, BN);
}

// Round 3
// 326.698 us; speedup vs baseline: 3.5779x; 1.5451x over previous
//
#include <hip/hip_runtime.h>

#define DD 128
#define NN 50000      // nodes (N)
#define BB 2          // batch
#define EE 500000     // edges
#define LN_EPS 1e-5f

typedef __attribute__((ext_vector_type(8))) short bf16x8;
typedef __attribute__((ext_vector_type(4))) float f32x4;

union FragU { unsigned short u[8]; bf16x8 v; };

__device__ __forceinline__ unsigned short f2bf(float x) {
  union { float f; unsigned u; } v; v.f = x;
  unsigned r = (v.u + 0x7FFFu + ((v.u >> 16) & 1u)) >> 16;
  return (unsigned short)r;
}
__device__ __forceinline__ float bf2f(unsigned short b) {
  union { unsigned u; float f; } v; v.u = ((unsigned)b) << 16;
  return v.f;
}
__device__ __forceinline__ float sigmoidf(float x) {
  return 1.0f / (1.0f + __expf(-x));
}

// ---------------------------------------------------------------------------
// Kernel 1: node dual-GEMM via MFMA, transposed-output formulation.
// D[f][node] = sum_k Wt[f][k] * h[node][k].  A = Wt (LDS bf16), B = h^T.
// Lane holds node = col = lane&15; features f = ft*16 + quad*4 + r.
// P (bf16) [row][128] = msgD * sigmoid(gateD).
// ---------------------------------------------------------------------------
__global__ __launch_bounds__(256) void k_node(
    const float* __restrict__ h, const float* __restrict__ gate_W,
    const float* __restrict__ msg_W, unsigned short* __restrict__ P, int BN)
{
  __shared__ unsigned short Wt[2][128][136];  // Wt[w][f][k], stride 136 (pad 8)

  const int t = threadIdx.x;
  // ---- stage both weight matrices, transposed, fp32 -> bf16 ----
  for (int w = 0; w < 2; w++) {
    const float* Wp = w ? msg_W : gate_W;
#pragma unroll
    for (int i = 0; i < 32; i++) {
      const int id = i * 256 + t;        // 8192 ids = 128 c x 64 k-pairs
      const int c  = id & 127;           // output feature (column of W)
      const int k2 = id >> 7;            // k-pair index, k = 2*k2, 2*k2+1
      const float a = Wp[(2 * k2)     * DD + c];
      const float b = Wp[(2 * k2 + 1) * DD + c];
      *(unsigned int*)&Wt[w][c][2 * k2] =
          (unsigned int)f2bf(a) | ((unsigned int)f2bf(b) << 16);
    }
  }
  __syncthreads();

  const int lane = t & 63;
  const int n16  = lane & 15;
  const int quad = lane >> 4;
  const int wave = t >> 6;
  const int nTiles = BN >> 4;                 // BN divisible by 16
  const int wstep  = gridDim.x * 4;

  for (int tile = blockIdx.x * 4 + wave; tile < nTiles; tile += wstep) {
    const int row0 = tile * 16;
    const size_t hbase = ((size_t)(row0 + n16)) * DD;

    // B-frags: h^T, lane reads h[row0+n16][ks*32 + quad*8 .. +7]
    FragU bf[4];
#pragma unroll
    for (int ks = 0; ks < 4; ks++) {
      const float4 x0 = *(const float4*)(h + hbase + ks * 32 + quad * 8);
      const float4 x1 = *(const float4*)(h + hbase + ks * 32 + quad * 8 + 4);
      bf[ks].u[0] = f2bf(x0.x); bf[ks].u[1] = f2bf(x0.y);
      bf[ks].u[2] = f2bf(x0.z); bf[ks].u[3] = f2bf(x0.w);
      bf[ks].u[4] = f2bf(x1.x); bf[ks].u[5] = f2bf(x1.y);
      bf[ks].u[6] = f2bf(x1.z); bf[ks].u[7] = f2bf(x1.w);
    }

    f32x4 accg[8], accm[8];
#pragma unroll
    for (int ftn = 0; ftn < 8; ftn++) { accg[ftn] = (f32x4)0.f; accm[ftn] = (f32x4)0.f; }

#pragma unroll
    for (int ft = 0; ft < 8; ft++) {
      const int frow = ft * 16 + n16;
#pragma unroll
      for (int ks = 0; ks < 4; ks++) {
        const bf16x8 ag = *(const bf16x8*)&Wt[0][frow][ks * 32 + quad * 8];
        const bf16x8 am = *(const bf16x8*)&Wt[1][frow][ks * 32 + quad * 8];
        accg[ft] = __builtin_amdgcn_mfma_f32_16x16x32_bf16(ag, bf[ks].v, accg[ft], 0, 0, 0);
        accm[ft] = __builtin_amdgcn_mfma_f32_16x16x32_bf16(am, bf[ks].v, accm[ft], 0, 0, 0);
      }
    }

    // epilogue: P[node][f] = msg * sigmoid(gate), node = row0+n16
    unsigned short* Pr = P + ((size_t)(row0 + n16)) * DD;
#pragma unroll
    for (int ft = 0; ft < 8; ft++) {
      float v0 = accm[ft][0] * sigmoidf(accg[ft][0]);
      float v1 = accm[ft][1] * sigmoidf(accg[ft][1]);
      float v2 = accm[ft][2] * sigmoidf(accg[ft][2]);
      float v3 = accm[ft][3] * sigmoidf(accg[ft][3]);
      uint2 o;
      o.x = (unsigned int)f2bf(v0) | ((unsigned int)f2bf(v1) << 16);
      o.y = (unsigned int)f2bf(v2) | ((unsigned int)f2bf(v3) << 16);
      *(uint2*)(Pr + ft * 16 + quad * 4) = o;
    }
  }
}

// ---------------------------------------------------------------------------
// CSR build: histogram -> block scans -> fill (counting sort by target).
// ---------------------------------------------------------------------------
__global__ __launch_bounds__(256) void k_hist(
    const int* __restrict__ etgt, int* __restrict__ deg)
{
  const int e = blockIdx.x * 256 + threadIdx.x;
  if (e < EE) atomicAdd(&deg[etgt[e]], 1);
}

__global__ __launch_bounds__(256) void k_scan_block(
    const int* __restrict__ deg, int* __restrict__ rstart,
    int* __restrict__ bsum, int N)
{
  __shared__ int s[256];
  const int i = blockIdx.x * 256 + threadIdx.x;
  const int v = (i < N) ? deg[i] : 0;
  s[threadIdx.x] = v;
  __syncthreads();
#pragma unroll
  for (int off = 1; off < 256; off <<= 1) {
    const int tv = (threadIdx.x >= off) ? s[threadIdx.x - off] : 0;
    __syncthreads();
    s[threadIdx.x] += tv;
    __syncthreads();
  }
  if (i < N) rstart[i] = s[threadIdx.x] - v;
  if (threadIdx.x == 255) bsum[blockIdx.x] = s[255];
}

__global__ __launch_bounds__(256) void k_scan_small(
    int* __restrict__ bsum, int* __restrict__ boff, int nb)
{
  __shared__ int s[256];
  const int v = (threadIdx.x < nb) ? bsum[threadIdx.x] : 0;
  s[threadIdx.x] = v;
  __syncthreads();
#pragma unroll
  for (int off = 1; off < 256; off <<= 1) {
    const int tv = (threadIdx.x >= off) ? s[threadIdx.x - off] : 0;
    __syncthreads();
    s[threadIdx.x] += tv;
    __syncthreads();
  }
  if (threadIdx.x < nb) boff[threadIdx.x] = s[threadIdx.x] - v;
}

__global__ __launch_bounds__(256) void k_add_off(
    int* __restrict__ rstart, const int* __restrict__ boff,
    int* __restrict__ cur, int N)
{
  const int i = blockIdx.x * 256 + threadIdx.x;
  if (i < N) {
    const int v = rstart[i] + boff[blockIdx.x];
    rstart[i] = v;
    cur[i] = v;
  }
}

__global__ __launch_bounds__(256) void k_fill(
    const int* __restrict__ esrc, const int* __restrict__ etgt,
    const int* __restrict__ erel, int* __restrict__ cur,
    int* __restrict__ packed)
{
  const int e = blockIdx.x * 256 + threadIdx.x;
  if (e < EE) {
    const int pos = atomicAdd(&cur[etgt[e]], 1);
    packed[pos] = esrc[e] | (erel[e] << 16);
  }
}

// ---------------------------------------------------------------------------
// Kernel 2: gather aggregation. One wave per node; lanes 0-31 batch 0,
// lanes 32-63 batch 1; each lane owns 4 cols. P bf16 in, h_agg bf16 out.
// ---------------------------------------------------------------------------
__global__ __launch_bounds__(256) void k_agg(
    const unsigned short* __restrict__ P, const float* __restrict__ rel_emb,
    const int* __restrict__ rstart, const int* __restrict__ packed,
    unsigned short* __restrict__ h_agg)
{
  const int node = blockIdx.x * 4 + (threadIdx.x >> 6);
  if (node >= NN) return;
  const int lane = threadIdx.x & 63;
  const int b    = lane >> 5;          // batch
  const int c4   = (lane & 31) * 4;    // 4 cols

  const int beg = rstart[node];
  const int end = (node == NN - 1) ? EE : rstart[node + 1];

  float a0 = 0.f, a1 = 0.f, a2 = 0.f, a3 = 0.f;
  for (int j = beg; j < end; j++) {
    const int p   = packed[j];
    const int src = p & 0xFFFF;
    const int rel = p >> 16;
    const float4 rv = *(const float4*)(rel_emb + (size_t)rel * DD + c4);
    const ushort4 pv = *(const ushort4*)(P + ((size_t)b * NN + src) * DD + c4);
    a0 += bf2f(pv.x) * rv.x;
    a1 += bf2f(pv.y) * rv.y;
    a2 += bf2f(pv.z) * rv.z;
    a3 += bf2f(pv.w) * rv.w;
  }
  uint2 o;
  o.x = (unsigned int)f2bf(a0) | ((unsigned int)f2bf(a1) << 16);
  o.y = (unsigned int)f2bf(a2) | ((unsigned int)f2bf(a3) << 16);
  *(uint2*)(h_agg + ((size_t)b * NN + node) * DD + c4) = o;
}

// ---------------------------------------------------------------------------
// Kernel 3: update GEMM (K=256) via MFMA (transposed-output) + bias + ReLU
// + residual + LayerNorm, fused. A = Wt_upd (LDS), B = [h | h_agg]^T.
// ---------------------------------------------------------------------------
__global__ __launch_bounds__(256) void k_update_ln(
    const float* __restrict__ h, const unsigned short* __restrict__ h_agg,
    const float* __restrict__ upd_W, const float* __restrict__ upd_b,
    const float* __restrict__ gamma, const float* __restrict__ beta,
    float* __restrict__ out, int BN)
{
  __shared__ unsigned short Wt[128][264];   // Wt[f][k], k in [0,256), pad 8

  const int t = threadIdx.x;
#pragma unroll
  for (int i = 0; i < 64; i++) {
    const int id = i * 256 + t;          // 16384 ids = 128 f x 128 k-pairs
    const int c  = id & 127;             // f
    const int k2 = id >> 7;              // k-pair
    const float a = upd_W[(2 * k2)     * DD + c];
    const float b = upd_W[(2 * k2 + 1) * DD + c];
    *(unsigned int*)&Wt[c][2 * k2] =
        (unsigned int)f2bf(a) | ((unsigned int)f2bf(b) << 16);
  }
  __syncthreads();

  const int lane = t & 63;
  const int n16  = lane & 15;
  const int quad = lane >> 4;
  const int wave = t >> 6;
  const int nTiles = BN >> 4;
  const int wstep  = gridDim.x * 4;

  for (int tile = blockIdx.x * 4 + wave; tile < nTiles; tile += wstep) {
    const int row0 = tile * 16;
    const size_t nrow = (size_t)(row0 + n16);

    FragU bf[8];
#pragma unroll
    for (int ks = 0; ks < 4; ks++) {   // k in [0,128): from h (fp32)
      const float4 x0 = *(const float4*)(h + nrow * DD + ks * 32 + quad * 8);
      const float4 x1 = *(const float4*)(h + nrow * DD + ks * 32 + quad * 8 + 4);
      bf[ks].u[0] = f2bf(x0.x); bf[ks].u[1] = f2bf(x0.y);
      bf[ks].u[2] = f2bf(x0.z); bf[ks].u[3] = f2bf(x0.w);
      bf[ks].u[4] = f2bf(x1.x); bf[ks].u[5] = f2bf(x1.y);
      bf[ks].u[6] = f2bf(x1.z); bf[ks].u[7] = f2bf(x1.w);
    }
#pragma unroll
    for (int ks = 4; ks < 8; ks++) {   // k in [128,256): from h_agg (bf16)
      bf[ks].v = *(const bf16x8*)(h_agg + nrow * DD + (ks - 4) * 32 + quad * 8);
    }

    f32x4 acc[8];
#pragma unroll
    for (int ftn = 0; ftn < 8; ftn++) acc[ftn] = (f32x4)0.f;

#pragma unroll
    for (int ft = 0; ft < 8; ft++) {
      const int frow = ft * 16 + n16;
#pragma unroll
      for (int ks = 0; ks < 8; ks++) {
        const bf16x8 a = *(const bf16x8*)&Wt[frow][ks * 32 + quad * 8];
        acc[ft] = __builtin_amdgcn_mfma_f32_16x16x32_bf16(a, bf[ks].v, acc[ft], 0, 0, 0);
      }
    }

    // epilogue: x = h + relu(upd + b); LayerNorm over f (quads hold r-groups)
    float xv[8][4];
    float s1 = 0.f, s2 = 0.f;
#pragma unroll
    for (int ft = 0; ft < 8; ft++) {
      const int f0 = ft * 16 + quad * 4;
      const float4 bv = *(const float4*)(upd_b + f0);
      const float4 hv = *(const float4*)(h + nrow * DD + f0);
      xv[ft][0] = hv.x + fmaxf(acc[ft][0] + bv.x, 0.f);
      xv[ft][1] = hv.y + fmaxf(acc[ft][1] + bv.y, 0.f);
      xv[ft][2] = hv.z + fmaxf(acc[ft][2] + bv.z, 0.f);
      xv[ft][3] = hv.w + fmaxf(acc[ft][3] + bv.w, 0.f);
#pragma unroll
      for (int r = 0; r < 4; r++) { s1 += xv[ft][r]; s2 += xv[ft][r] * xv[ft][r]; }
    }
    s1 += __shfl_xor(s1, 16, 64); s2 += __shfl_xor(s2, 16, 64);
    s1 += __shfl_xor(s1, 32, 64); s2 += __shfl_xor(s2, 32, 64);

    const float mu   = s1 * (1.0f / DD);
    const float var  = s2 * (1.0f / DD) - mu * mu;
    const float rstd = rsqrtf(var + LN_EPS);

#pragma unroll
    for (int ft = 0; ft < 8; ft++) {
      const int f0 = ft * 16 + quad * 4;
      const float4 gv = *(const float4*)(gamma + f0);
      const float4 bt = *(const float4*)(beta + f0);
      float4 o;
      o.x = (xv[ft][0] - mu) * rstd * gv.x + bt.x;
      o.y = (xv[ft][1] - mu) * rstd * gv.y + bt.y;
      o.z = (xv[ft][2] - mu) * rstd * gv.z + bt.z;
      o.w = (xv[ft][3] - mu) * rstd * gv.w + bt.w;
      *(float4*)(out + nrow * DD + f0) = o;
    }
  }
}

// ---------------------------------------------------------------------------
extern "C" void kernel_launch(void* const* d_in, const int* in_sizes, int n_in,
                              void* d_out, int out_size, void* d_ws, size_t ws_size,
                              hipStream_t stream) {
  const float* h       = (const float*)d_in[0];
  const int*   esrc    = (const int*)d_in[1];
  const int*   etgt    = (const int*)d_in[2];
  const int*   erel    = (const int*)d_in[3];
  const float* msg_W   = (const float*)d_in[5];
  const float* rel_emb = (const float*)d_in[6];
  const float* gate_W  = (const float*)d_in[7];
  const float* upd_W   = (const float*)d_in[8];
  const float* upd_b   = (const float*)d_in[9];
  const float* gamma   = (const float*)d_in[10];
  const float* beta    = (const float*)d_in[11];
  float*       out     = (float*)d_out;

  const int BN = in_sizes[0] / DD;   // 100000

  unsigned short* P     = (unsigned short*)d_ws;         // BN*DD bf16 (25.6MB)
  unsigned short* h_agg = P + (size_t)BN * DD;           // BN*DD bf16 (25.6MB)
  int* deg    = (int*)(h_agg + (size_t)BN * DD);
  int* rstart = deg + NN;
  int* cur    = rstart + NN;
  int* bsum   = cur + NN;
  int* boff   = bsum + 256;
  int* packed = boff + 256;                              // EE ints

  const int nbN = (NN + 255) / 256;
  const int nbE = (EE + 255) / 256;

  hipMemsetAsync(deg, 0, NN * sizeof(int), stream);

  k_node<<<512, 256, 0, stream>>>(h, gate_W, msg_W, P, BN);

  k_hist<<<nbE, 256, 0, stream>>>(etgt, deg);
  k_scan_block<<<nbN, 256, 0, stream>>>(deg, rstart, bsum, NN);
  k_scan_small<<<1, 256, 0, stream>>>(bsum, boff, nbN);
  k_add_off<<<nbN, 256, 0, stream>>>(rstart, boff, cur, NN);
  k_fill<<<nbE, 256, 0, stream>>>(esrc, etgt, erel, cur, packed);

  k_agg<<<(NN + 3) / 4, 256, 0, stream>>>(P, rel_emb, rstart, packed, h_agg);

  k_update_ln<<<512, 256, 0, stream>>>(h, h_agg, upd_W, upd_b,
                                       gamma, beta, out, BN);
}

// Round 4
// 285.339 us; speedup vs baseline: 4.0965x; 1.1449x over previous
//
#include <hip/hip_runtime.h>

#define DD 128
#define NN 50000      // nodes (N)
#define BB 2          // batch
#define EE 500000     // edges
#define LN_EPS 1e-5f

typedef __attribute__((ext_vector_type(8))) short bf16x8;
typedef __attribute__((ext_vector_type(4))) float f32x4;

union FragU { unsigned short u[8]; bf16x8 v; };

__device__ __forceinline__ unsigned short f2bf(float x) {
  union { float f; unsigned u; } v; v.f = x;
  unsigned r = (v.u + 0x7FFFu + ((v.u >> 16) & 1u)) >> 16;
  return (unsigned short)r;
}
__device__ __forceinline__ float bfbits(short s) {
  union { unsigned u; float f; } v;
  v.u = ((unsigned)(unsigned short)s) << 16;
  return v.f;
}
__device__ __forceinline__ float sigmoidf(float x) {
  return 1.0f / (1.0f + __expf(-x));
}

// ---------------------------------------------------------------------------
// k_prep: zero deg + convert rel_emb fp32 -> bf16 (relb[r][128]).
// ---------------------------------------------------------------------------
__global__ __launch_bounds__(256) void k_prep(
    const float* __restrict__ rel_emb, unsigned short* __restrict__ relb,
    int* __restrict__ deg)
{
  const int id = blockIdx.x * 256 + threadIdx.x;
  if (id < 500 * DD / 2) {
    const float a = rel_emb[2 * id];
    const float b = rel_emb[2 * id + 1];
    *(unsigned int*)&relb[2 * id] =
        (unsigned int)f2bf(a) | ((unsigned int)f2bf(b) << 16);
  }
  if (id < NN) deg[id] = 0;
}

// ---------------------------------------------------------------------------
// Kernel 1: node dual-GEMM via MFMA, transposed-output formulation.
// Also emits hb (bf16 copy of h) and P interleaved [node][b*128+f].
// ---------------------------------------------------------------------------
__global__ __launch_bounds__(256) void k_node(
    const float* __restrict__ h, const float* __restrict__ gate_W,
    const float* __restrict__ msg_W, unsigned short* __restrict__ P,
    unsigned short* __restrict__ hb, int BN)
{
  __shared__ unsigned short Wt[2][128][136];  // Wt[w][f][k], stride 136 (pad 8)

  const int t = threadIdx.x;
  for (int w = 0; w < 2; w++) {
    const float* Wp = w ? msg_W : gate_W;
#pragma unroll
    for (int i = 0; i < 32; i++) {
      const int id = i * 256 + t;
      const int c  = id & 127;
      const int k2 = id >> 7;
      const float a = Wp[(2 * k2)     * DD + c];
      const float b = Wp[(2 * k2 + 1) * DD + c];
      *(unsigned int*)&Wt[w][c][2 * k2] =
          (unsigned int)f2bf(a) | ((unsigned int)f2bf(b) << 16);
    }
  }
  __syncthreads();

  const int lane = t & 63;
  const int n16  = lane & 15;
  const int quad = lane >> 4;
  const int wave = t >> 6;
  const int nTiles = BN >> 4;
  const int wstep  = gridDim.x * 4;

  for (int tile = blockIdx.x * 4 + wave; tile < nTiles; tile += wstep) {
    const int row0 = tile * 16;
    const int b    = (row0 >= NN) ? 1 : 0;       // tile never straddles batch
    const int node = row0 - b * NN + n16;
    const size_t hbase = ((size_t)(row0 + n16)) * DD;

    FragU bf[4];
#pragma unroll
    for (int ks = 0; ks < 4; ks++) {
      const float4 x0 = *(const float4*)(h + hbase + ks * 32 + quad * 8);
      const float4 x1 = *(const float4*)(h + hbase + ks * 32 + quad * 8 + 4);
      bf[ks].u[0] = f2bf(x0.x); bf[ks].u[1] = f2bf(x0.y);
      bf[ks].u[2] = f2bf(x0.z); bf[ks].u[3] = f2bf(x0.w);
      bf[ks].u[4] = f2bf(x1.x); bf[ks].u[5] = f2bf(x1.y);
      bf[ks].u[6] = f2bf(x1.z); bf[ks].u[7] = f2bf(x1.w);
      *(bf16x8*)(hb + hbase + ks * 32 + quad * 8) = bf[ks].v;  // bf16 h copy
    }

    f32x4 accg[8], accm[8];
#pragma unroll
    for (int ftn = 0; ftn < 8; ftn++) { accg[ftn] = (f32x4)0.f; accm[ftn] = (f32x4)0.f; }

#pragma unroll
    for (int ft = 0; ft < 8; ft++) {
      const int frow = ft * 16 + n16;
#pragma unroll
      for (int ks = 0; ks < 4; ks++) {
        const bf16x8 ag = *(const bf16x8*)&Wt[0][frow][ks * 32 + quad * 8];
        const bf16x8 am = *(const bf16x8*)&Wt[1][frow][ks * 32 + quad * 8];
        accg[ft] = __builtin_amdgcn_mfma_f32_16x16x32_bf16(ag, bf[ks].v, accg[ft], 0, 0, 0);
        accm[ft] = __builtin_amdgcn_mfma_f32_16x16x32_bf16(am, bf[ks].v, accm[ft], 0, 0, 0);
      }
    }

    // P[node][b*128 + f]
    unsigned short* Pr = P + (size_t)node * 256 + b * 128;
#pragma unroll
    for (int ft = 0; ft < 8; ft++) {
      float v0 = accm[ft][0] * sigmoidf(accg[ft][0]);
      float v1 = accm[ft][1] * sigmoidf(accg[ft][1]);
      float v2 = accm[ft][2] * sigmoidf(accg[ft][2]);
      float v3 = accm[ft][3] * sigmoidf(accg[ft][3]);
      uint2 o;
      o.x = (unsigned int)f2bf(v0) | ((unsigned int)f2bf(v1) << 16);
      o.y = (unsigned int)f2bf(v2) | ((unsigned int)f2bf(v3) << 16);
      *(uint2*)(Pr + ft * 16 + quad * 4) = o;
    }
  }
}

// ---------------------------------------------------------------------------
// CSR build: histogram -> block scans -> fill (counting sort by target).
// ---------------------------------------------------------------------------
__global__ __launch_bounds__(256) void k_hist(
    const int* __restrict__ etgt, int* __restrict__ deg)
{
  const int e = blockIdx.x * 256 + threadIdx.x;
  if (e < EE) atomicAdd(&deg[etgt[e]], 1);
}

__global__ __launch_bounds__(256) void k_scan_block(
    const int* __restrict__ deg, int* __restrict__ rstart,
    int* __restrict__ bsum, int N)
{
  __shared__ int s[256];
  const int i = blockIdx.x * 256 + threadIdx.x;
  const int v = (i < N) ? deg[i] : 0;
  s[threadIdx.x] = v;
  __syncthreads();
#pragma unroll
  for (int off = 1; off < 256; off <<= 1) {
    const int tv = (threadIdx.x >= off) ? s[threadIdx.x - off] : 0;
    __syncthreads();
    s[threadIdx.x] += tv;
    __syncthreads();
  }
  if (i < N) rstart[i] = s[threadIdx.x] - v;
  if (threadIdx.x == 255) bsum[blockIdx.x] = s[255];
}

__global__ __launch_bounds__(256) void k_scan_small(
    int* __restrict__ bsum, int* __restrict__ boff, int nb)
{
  __shared__ int s[256];
  const int v = (threadIdx.x < nb) ? bsum[threadIdx.x] : 0;
  s[threadIdx.x] = v;
  __syncthreads();
#pragma unroll
  for (int off = 1; off < 256; off <<= 1) {
    const int tv = (threadIdx.x >= off) ? s[threadIdx.x - off] : 0;
    __syncthreads();
    s[threadIdx.x] += tv;
    __syncthreads();
  }
  if (threadIdx.x < nb) boff[threadIdx.x] = s[threadIdx.x] - v;
}

__global__ __launch_bounds__(256) void k_add_off(
    int* __restrict__ rstart, const int* __restrict__ boff,
    int* __restrict__ cur, int N)
{
  const int i = blockIdx.x * 256 + threadIdx.x;
  if (i < N) {
    const int v = rstart[i] + boff[blockIdx.x];
    rstart[i] = v;
    cur[i] = v;
  }
}

__global__ __launch_bounds__(256) void k_fill(
    const int* __restrict__ esrc, const int* __restrict__ etgt,
    const int* __restrict__ erel, int* __restrict__ cur,
    int* __restrict__ packed)
{
  const int e = blockIdx.x * 256 + threadIdx.x;
  if (e < EE) {
    const int pos = atomicAdd(&cur[etgt[e]], 1);
    packed[pos] = esrc[e] | (erel[e] << 16);
  }
}

// ---------------------------------------------------------------------------
// Kernel 2: gather aggregation. One wave per node. Half-wave per edge
// (2 edges in flight), 2x unrolled (4 edge-gathers outstanding). Lane owns
// 8 cols of the interleaved [node][256] row -> 16B loads/stores.
// ---------------------------------------------------------------------------
__global__ __launch_bounds__(256) void k_agg(
    const unsigned short* __restrict__ P, const unsigned short* __restrict__ relb,
    const int* __restrict__ rstart, const int* __restrict__ packed,
    unsigned short* __restrict__ h_agg)
{
  const int node = blockIdx.x * 4 + (threadIdx.x >> 6);
  if (node >= NN) return;
  const int lane = threadIdx.x & 63;
  const int half = lane >> 5;          // which edge of the in-flight pair
  const int c8   = (lane & 31) * 8;    // col in [0,256)
  const int rc   = c8 & 127;           // rel col (batches share rel row)

  const int beg = rstart[node];
  const int end = (node == NN - 1) ? EE : rstart[node + 1];

  float acc[8];
#pragma unroll
  for (int i = 0; i < 8; i++) acc[i] = 0.f;

  int j = beg + half;
  for (; j + 2 < end; j += 4) {        // 2 edges per half in flight
    const int p0 = packed[j];
    const int p1 = packed[j + 2];
    const bf16x8 pv0 = *(const bf16x8*)(P + (size_t)(p0 & 0xFFFF) * 256 + c8);
    const bf16x8 rv0 = *(const bf16x8*)(relb + (size_t)(p0 >> 16) * DD + rc);
    const bf16x8 pv1 = *(const bf16x8*)(P + (size_t)(p1 & 0xFFFF) * 256 + c8);
    const bf16x8 rv1 = *(const bf16x8*)(relb + (size_t)(p1 >> 16) * DD + rc);
#pragma unroll
    for (int i = 0; i < 8; i++) {
      acc[i] += bfbits(pv0[i]) * bfbits(rv0[i]);
      acc[i] += bfbits(pv1[i]) * bfbits(rv1[i]);
    }
  }
  for (; j < end; j += 2) {
    const int p0 = packed[j];
    const bf16x8 pv0 = *(const bf16x8*)(P + (size_t)(p0 & 0xFFFF) * 256 + c8);
    const bf16x8 rv0 = *(const bf16x8*)(relb + (size_t)(p0 >> 16) * DD + rc);
#pragma unroll
    for (int i = 0; i < 8; i++) acc[i] += bfbits(pv0[i]) * bfbits(rv0[i]);
  }

  // combine the two halves
#pragma unroll
  for (int i = 0; i < 8; i++) acc[i] += __shfl_xor(acc[i], 32, 64);

  if (half == 0) {
    uint4 o;
    o.x = (unsigned int)f2bf(acc[0]) | ((unsigned int)f2bf(acc[1]) << 16);
    o.y = (unsigned int)f2bf(acc[2]) | ((unsigned int)f2bf(acc[3]) << 16);
    o.z = (unsigned int)f2bf(acc[4]) | ((unsigned int)f2bf(acc[5]) << 16);
    o.w = (unsigned int)f2bf(acc[6]) | ((unsigned int)f2bf(acc[7]) << 16);
    *(uint4*)(h_agg + (size_t)node * 256 + c8) = o;
  }
}

// ---------------------------------------------------------------------------
// Kernel 3: update GEMM (K=256) via MFMA + bias + ReLU + residual + LN.
// B-frags: k<128 from hb (bf16), k>=128 from h_agg interleaved (bf16).
// ---------------------------------------------------------------------------
__global__ __launch_bounds__(256) void k_update_ln(
    const float* __restrict__ h, const unsigned short* __restrict__ hb,
    const unsigned short* __restrict__ h_agg,
    const float* __restrict__ upd_W, const float* __restrict__ upd_b,
    const float* __restrict__ gamma, const float* __restrict__ beta,
    float* __restrict__ out, int BN)
{
  __shared__ unsigned short Wt[128][264];

  const int t = threadIdx.x;
#pragma unroll
  for (int i = 0; i < 64; i++) {
    const int id = i * 256 + t;
    const int c  = id & 127;
    const int k2 = id >> 7;
    const float a = upd_W[(2 * k2)     * DD + c];
    const float b = upd_W[(2 * k2 + 1) * DD + c];
    *(unsigned int*)&Wt[c][2 * k2] =
        (unsigned int)f2bf(a) | ((unsigned int)f2bf(b) << 16);
  }
  __syncthreads();

  const int lane = t & 63;
  const int n16  = lane & 15;
  const int quad = lane >> 4;
  const int wave = t >> 6;
  const int nTiles = BN >> 4;
  const int wstep  = gridDim.x * 4;

  for (int tile = blockIdx.x * 4 + wave; tile < nTiles; tile += wstep) {
    const int row0 = tile * 16;
    const int b    = (row0 >= NN) ? 1 : 0;
    const int node = row0 - b * NN + n16;
    const size_t nrow = (size_t)(row0 + n16);

    bf16x8 bfrag[8];
#pragma unroll
    for (int ks = 0; ks < 4; ks++)
      bfrag[ks] = *(const bf16x8*)(hb + nrow * DD + ks * 32 + quad * 8);
#pragma unroll
    for (int ks = 4; ks < 8; ks++)
      bfrag[ks] = *(const bf16x8*)(h_agg + (size_t)node * 256 + b * 128 +
                                   (ks - 4) * 32 + quad * 8);

    f32x4 acc[8];
#pragma unroll
    for (int ftn = 0; ftn < 8; ftn++) acc[ftn] = (f32x4)0.f;

#pragma unroll
    for (int ft = 0; ft < 8; ft++) {
      const int frow = ft * 16 + n16;
#pragma unroll
      for (int ks = 0; ks < 8; ks++) {
        const bf16x8 a = *(const bf16x8*)&Wt[frow][ks * 32 + quad * 8];
        acc[ft] = __builtin_amdgcn_mfma_f32_16x16x32_bf16(a, bfrag[ks], acc[ft], 0, 0, 0);
      }
    }

    float xv[8][4];
    float s1 = 0.f, s2 = 0.f;
#pragma unroll
    for (int ft = 0; ft < 8; ft++) {
      const int f0 = ft * 16 + quad * 4;
      const float4 bv = *(const float4*)(upd_b + f0);
      const float4 hv = *(const float4*)(h + nrow * DD + f0);
      xv[ft][0] = hv.x + fmaxf(acc[ft][0] + bv.x, 0.f);
      xv[ft][1] = hv.y + fmaxf(acc[ft][1] + bv.y, 0.f);
      xv[ft][2] = hv.z + fmaxf(acc[ft][2] + bv.z, 0.f);
      xv[ft][3] = hv.w + fmaxf(acc[ft][3] + bv.w, 0.f);
#pragma unroll
      for (int r = 0; r < 4; r++) { s1 += xv[ft][r]; s2 += xv[ft][r] * xv[ft][r]; }
    }
    s1 += __shfl_xor(s1, 16, 64); s2 += __shfl_xor(s2, 16, 64);
    s1 += __shfl_xor(s1, 32, 64); s2 += __shfl_xor(s2, 32, 64);

    const float mu   = s1 * (1.0f / DD);
    const float var  = s2 * (1.0f / DD) - mu * mu;
    const float rstd = rsqrtf(var + LN_EPS);

#pragma unroll
    for (int ft = 0; ft < 8; ft++) {
      const int f0 = ft * 16 + quad * 4;
      const float4 gv = *(const float4*)(gamma + f0);
      const float4 bt = *(const float4*)(beta + f0);
      float4 o;
      o.x = (xv[ft][0] - mu) * rstd * gv.x + bt.x;
      o.y = (xv[ft][1] - mu) * rstd * gv.y + bt.y;
      o.z = (xv[ft][2] - mu) * rstd * gv.z + bt.z;
      o.w = (xv[ft][3] - mu) * rstd * gv.w + bt.w;
      *(float4*)(out + nrow * DD + f0) = o;
    }
  }
}

// ---------------------------------------------------------------------------
extern "C" void kernel_launch(void* const* d_in, const int* in_sizes, int n_in,
                              void* d_out, int out_size, void* d_ws, size_t ws_size,
                              hipStream_t stream) {
  const float* h       = (const float*)d_in[0];
  const int*   esrc    = (const int*)d_in[1];
  const int*   etgt    = (const int*)d_in[2];
  const int*   erel    = (const int*)d_in[3];
  const float* msg_W   = (const float*)d_in[5];
  const float* rel_emb = (const float*)d_in[6];
  const float* gate_W  = (const float*)d_in[7];
  const float* upd_W   = (const float*)d_in[8];
  const float* upd_b   = (const float*)d_in[9];
  const float* gamma   = (const float*)d_in[10];
  const float* beta    = (const float*)d_in[11];
  float*       out     = (float*)d_out;

  const int BN = in_sizes[0] / DD;   // 100000

  unsigned short* P     = (unsigned short*)d_ws;          // NN*256 bf16
  unsigned short* h_agg = P + (size_t)NN * 256;           // NN*256 bf16
  unsigned short* hb    = h_agg + (size_t)NN * 256;       // BN*128 bf16
  unsigned short* relb  = hb + (size_t)BN * DD;           // 500*128 bf16
  int* deg    = (int*)(relb + 500 * DD);
  int* rstart = deg + NN;
  int* cur    = rstart + NN;
  int* bsum   = cur + NN;
  int* boff   = bsum + 256;
  int* packed = boff + 256;                               // EE ints

  const int nbN = (NN + 255) / 256;
  const int nbE = (EE + 255) / 256;

  k_prep<<<nbN, 256, 0, stream>>>(rel_emb, relb, deg);

  k_node<<<512, 256, 0, stream>>>(h, gate_W, msg_W, P, hb, BN);

  k_hist<<<nbE, 256, 0, stream>>>(etgt, deg);
  k_scan_block<<<nbN, 256, 0, stream>>>(deg, rstart, bsum, NN);
  k_scan_small<<<1, 256, 0, stream>>>(bsum, boff, nbN);
  k_add_off<<<nbN, 256, 0, stream>>>(rstart, boff, cur, NN);
  k_fill<<<nbE, 256, 0, stream>>>(esrc, etgt, erel, cur, packed);

  k_agg<<<(NN + 3) / 4, 256, 0, stream>>>(P, relb, rstart, packed, h_agg);

  k_update_ln<<<512, 256, 0, stream>>>(h, hb, h_agg, upd_W, upd_b,
                                       gamma, beta, out, BN);
}